// Round 14
// baseline (295.351 us; speedup 1.0000x reference)
//
#include <hip/hip_runtime.h>

#define ZD 64
#define RD 128
#define HIDDEN 512
#define NSTEP 100
#define OUT_PITCH 6464              // 101*64
#define DT_F 0.01f
#define HSTR 520                    // Hs row stride (shorts)
#define XSTR 72                     // Xb row stride (shorts)
#define PSTR 76                     // Ps row stride (floats)

static const size_t LW_OFF = 52953088ull;   // 8192*101*64
static const size_t NG_OFF = 52961280ull;   // + 8192

typedef __attribute__((ext_vector_type(4))) float  f32x4;
typedef __attribute__((ext_vector_type(8))) __bf16 bf16x8;
typedef __attribute__((ext_vector_type(4))) short  s16x4;
typedef __attribute__((ext_vector_type(8))) short  s16x8;

__device__ __forceinline__ short f2bs(float f) {
    return __builtin_bit_cast(short, (__bf16)f);
}
__device__ __forceinline__ float bs2f(short s) {
    return __builtin_bit_cast(float, ((unsigned)(unsigned short)s) << 16);
}
__device__ __forceinline__ float tanh_fast(float x) {
    float e = __builtin_amdgcn_exp2f(x * 2.88539008177793f);
    float r = __builtin_amdgcn_rcpf(e + 1.0f);
    return fmaf(-2.0f, r, 1.0f);
}
// LDS barrier safe under wave-uniform divergence (validated R13):
// drains lgkmcnt, leaves vmcnt in flight.
__device__ __forceinline__ void barrier_lds() {
    asm volatile("s_waitcnt lgkmcnt(0)" ::: "memory");
    __builtin_amdgcn_s_barrier();
    asm volatile("" ::: "memory");
}

// ---------------------------------------------------------------------------
// sim_kernel: persistent scan, wave-group specialized via TWO SEPARATE
// straight-line loops (fixes R11's union-live-range spills).
// 256 blocks x 1024 threads (16 waves), 32 rows = halves A(0-15)/B(16-31).
// grp0 (waves 0-7) owns A:  G1A(0); [ G2A | UA | G1A(s+1) ] x100
// grp1 (waves 8-15) owns B: (idle); [ G1B | G2B | UB       ] x100
// -> every barrier interval mixes VALU-heavy G1 with DS-heavy G2/U on
// different waves (2+2 per SIMD). Same barrier count both paths.
// Per-wave: w1f 32 + w2f 32 (AGPR-eligible = 64) + prefb 8 + state ~15.
// ---------------------------------------------------------------------------
__global__ __launch_bounds__(1024, 1)
void sim_kernel(
    const float* __restrict__ r, const float* __restrict__ noises,
    const float* __restrict__ x0, const float* __restrict__ W1,
    const float* __restrict__ b1, const float* __restrict__ W2,
    const float* __restrict__ b2, const float* __restrict__ bmax,
    const float* __restrict__ bmin, const float* __restrict__ mu,
    float* __restrict__ out)
{
    __shared__ unsigned short Xb[2][16 * XSTR];       // 4608 B
    __shared__ unsigned short Hs[2][16 * HSTR];       // 33280 B
    __shared__ float Ps[2][4][16][PSTR];              // 38912 B
    __shared__ float w1ts[HIDDEN];                    // 2048 B
    __shared__ float tT[NSTEP], tG[NSTEP], tSd[NSTEP], tCd[NSTEP], tCs[NSTEP];

    const int tid  = threadIdx.x;
    const int lane = tid & 63;
    const int wave = tid >> 6;       // 0..15
    const int g4   = lane >> 4;      // 0..3
    const int l16  = lane & 15;
    const int row0 = blockIdx.x * 32;

    const int grp = wave >> 3;       // 0 = half A, 1 = half B
    const int q   = wave & 7;        // role within group
    const int zh  = q & 1, kq = q >> 1;   // G2 roles

    unsigned short* Xh = Xb[grp];
    unsigned short* Hh = Hs[grp];

    // ---- step tables ----
    if (tid < NSTEP) {
        float spmax = log1pf(expf(bmax[0]));
        float spmin = log1pf(expf(bmin[0]));
        float a_ = spmax - spmin;
        float c_ = spmin;
        const float PI_ = 3.14159265358979323846f;
        float k = (float)tid;
        float t0 = k * DT_F, t1 = (k + 1.0f) * DT_F;
        float inv2pi = 1.0f / (2.0f * PI_);
        float F0 = a_ * sinf(PI_ * t0) * inv2pi + (0.5f * a_ + c_) * t0;
        float F1 = a_ * sinf(PI_ * t1) * inv2pi + (0.5f * a_ + c_) * t1;
        float al = 1.0f - expf(-2.0f * (F1 - F0));
        float gg = 1.0f - sqrtf(1.0f - al);
        float kap = (gg * gg) / al;
        tT[tid] = t0; tG[tid] = gg; tSd[tid] = sqrtf(al);
        tCd[tid] = -2.0f * kap; tCs[tid] = -2.0f * sqrtf(kap);
    }
    if (tid < HIDDEN) w1ts[tid] = W1[(size_t)192 * HIDDEN + tid];

    // ---- U indexing: 512 threads/group cover 16 rows x 64 cols ----
    const int urow = (q << 1) | (lane >> 5);      // 0..15
    const int uc0  = lane & 31;
    const int uc1  = uc0 + 32;
    const size_t grow = (size_t)(row0 + grp * 16 + urow);

    // ---- x state init + x_t[:,0,:] + Xb ----
    float xu0 = x0[grow * ZD + uc0];
    float xu1 = x0[grow * ZD + uc1];
    out[grow * OUT_PITCH + uc0] = xu0;
    out[grow * OUT_PITCH + uc1] = xu1;
    Xh[urow * XSTR + uc0] = (unsigned short)f2bs(xu0);
    Xh[urow * XSTR + uc1] = (unsigned short)f2bs(xu1);
    const float bb0 = b2[uc0], bb1 = b2[uc1];
    float lw = 0.0f;

    // ---- pre-fragments via MFMA (own half's rows), packed bf16 ----
    s16x4 prefb[4];
    {
        bf16x8 rf[4];
        const float* rp = r + (size_t)(row0 + grp * 16 + l16) * RD;
        #pragma unroll
        for (int kc = 0; kc < 4; ++kc) {
            f32x4 lo = *(const f32x4*)(rp + kc * 32 + g4 * 8);
            f32x4 hi = *(const f32x4*)(rp + kc * 32 + g4 * 8 + 4);
            bf16x8 v;
            v[0]=(__bf16)lo[0]; v[1]=(__bf16)lo[1]; v[2]=(__bf16)lo[2]; v[3]=(__bf16)lo[3];
            v[4]=(__bf16)hi[0]; v[5]=(__bf16)hi[1]; v[6]=(__bf16)hi[2]; v[7]=(__bf16)hi[3];
            rf[kc] = v;
        }
        #pragma unroll
        for (int j2 = 0; j2 < 4; ++j2) {
            int n  = (q * 4 + j2) * 16 + l16;
            int n0 = (q * 4 + j2) * 16 + g4 * 4;
            f32x4 acc = *(const f32x4*)(b1 + n0);
            #pragma unroll
            for (int kc = 0; kc < 4; ++kc) {
                bf16x8 w;
                #pragma unroll
                for (int j = 0; j < 8; ++j)
                    w[j] = (__bf16)W1[(size_t)(64 + kc * 32 + g4 * 8 + j) * HIDDEN + n];
                acc = __builtin_amdgcn_mfma_f32_16x16x32_bf16(w, rf[kc], acc, 0, 0, 0);
            }
            s16x4 pb;
            pb[0] = f2bs(acc[0]); pb[1] = f2bs(acc[1]);
            pb[2] = f2bs(acc[2]); pb[3] = f2bs(acc[3]);
            prefb[j2] = pb;
        }
    }

    // ---- persistent weight fragments (MFMA-only -> AGPR-eligible) ----
    bf16x8 w1f[4][2];                // [j2][kc], n = (q*4+j2)*16+l16
    #pragma unroll
    for (int j2 = 0; j2 < 4; ++j2) {
        int n = (q * 4 + j2) * 16 + l16;
        #pragma unroll
        for (int kc = 0; kc < 2; ++kc) {
            bf16x8 v;
            #pragma unroll
            for (int j = 0; j < 8; ++j)
                v[j] = (__bf16)W1[(size_t)(kc * 32 + g4 * 8 + j) * HIDDEN + n];
            w1f[j2][kc] = v;
        }
    }
    bf16x8 w2f[2][4];                // [zt2][i], (zh, kq) role
    #pragma unroll
    for (int zt2 = 0; zt2 < 2; ++zt2) {
        int n2 = (zh * 2 + zt2) * 16 + l16;
        #pragma unroll
        for (int i = 0; i < 4; ++i) {
            bf16x8 v;
            #pragma unroll
            for (int j = 0; j < 8; ++j)
                v[j] = (__bf16)W2[(size_t)(kq * 128 + i * 32 + g4 * 8 + j) * ZD + n2];
            w2f[zt2][i] = v;
        }
    }

// ---- phase bodies as macros: identical code at every expansion site ----
#define G1_BODY(TVAL) do {                                                   \
    float t_ = (TVAL);                                                       \
    s16x8 xb0 = *(const s16x8*)(Xh + l16 * XSTR + g4 * 8);                   \
    s16x8 xb1 = *(const s16x8*)(Xh + l16 * XSTR + 32 + g4 * 8);              \
    _Pragma("unroll")                                                        \
    for (int j2 = 0; j2 < 4; ++j2) {                                         \
        int n0 = (q * 4 + j2) * 16 + g4 * 4;                                 \
        f32x4 wt = *(const f32x4*)(w1ts + n0);                               \
        s16x4 pb = prefb[j2];                                                \
        f32x4 acc;                                                           \
        acc[0] = fmaf(t_, wt[0], bs2f(pb[0]));                               \
        acc[1] = fmaf(t_, wt[1], bs2f(pb[1]));                               \
        acc[2] = fmaf(t_, wt[2], bs2f(pb[2]));                               \
        acc[3] = fmaf(t_, wt[3], bs2f(pb[3]));                               \
        acc = __builtin_amdgcn_mfma_f32_16x16x32_bf16(                       \
            w1f[j2][0], __builtin_bit_cast(bf16x8, xb0), acc, 0, 0, 0);      \
        acc = __builtin_amdgcn_mfma_f32_16x16x32_bf16(                       \
            w1f[j2][1], __builtin_bit_cast(bf16x8, xb1), acc, 0, 0, 0);      \
        s16x4 hv;                                                            \
        hv[0] = f2bs(tanh_fast(acc[0]));                                     \
        hv[1] = f2bs(tanh_fast(acc[1]));                                     \
        hv[2] = f2bs(tanh_fast(acc[2]));                                     \
        hv[3] = f2bs(tanh_fast(acc[3]));                                     \
        *(s16x4*)(Hh + l16 * HSTR + n0) = hv;                                \
    }                                                                        \
} while (0)

#define G2_BODY() do {                                                       \
    int base_ = l16 * HSTR + kq * 128 + g4 * 8;                              \
    f32x4 aA = { 0.f, 0.f, 0.f, 0.f };                                       \
    f32x4 aB = { 0.f, 0.f, 0.f, 0.f };                                       \
    _Pragma("unroll")                                                        \
    for (int i = 0; i < 4; ++i) {                                            \
        s16x8 h = *(const s16x8*)(Hh + base_ + i * 32);                      \
        aA = __builtin_amdgcn_mfma_f32_16x16x32_bf16(                        \
            w2f[0][i], __builtin_bit_cast(bf16x8, h), aA, 0, 0, 0);          \
        aB = __builtin_amdgcn_mfma_f32_16x16x32_bf16(                        \
            w2f[1][i], __builtin_bit_cast(bf16x8, h), aB, 0, 0, 0);          \
    }                                                                        \
    *(f32x4*)(&Ps[grp][kq][l16][(zh * 2 + 0) * 16 + g4 * 4]) = aA;           \
    *(f32x4*)(&Ps[grp][kq][l16][(zh * 2 + 1) * 16 + g4 * 4]) = aB;           \
} while (0)

#define U_BODY(S, NZ0, NZ1) do {                                             \
    float gg = tG[S], sdv = tSd[S], cd = tCd[S], cs = tCs[S];                \
    float s0 = ((Ps[grp][0][urow][uc0] + Ps[grp][1][urow][uc0])              \
              + (Ps[grp][2][urow][uc0] + Ps[grp][3][urow][uc0])) + bb0;      \
    float s1 = ((Ps[grp][0][urow][uc1] + Ps[grp][1][urow][uc1])              \
              + (Ps[grp][2][urow][uc1] + Ps[grp][3][urow][uc1])) + bb1;      \
    float xn0 = xu0 + gg * (2.0f * s0 - xu0) + sdv * (NZ0);                  \
    float xn1 = xu1 + gg * (2.0f * s1 - xu1) + sdv * (NZ1);                  \
    out[grow * OUT_PITCH + (size_t)((S) + 1) * ZD + uc0] = xn0;              \
    out[grow * OUT_PITCH + (size_t)((S) + 1) * ZD + uc1] = xn1;              \
    Xh[urow * XSTR + uc0] = (unsigned short)f2bs(xn0);                       \
    Xh[urow * XSTR + uc1] = (unsigned short)f2bs(xn1);                       \
    lw += cd * (s0 * s0 + s1 * s1) + cs * (s0 * (NZ0) + s1 * (NZ1));         \
    xu0 = xn0; xu1 = xn1;                                                    \
} while (0)

    __syncthreads();

    if (grp == 0) {
        // -------- half A: G2 -> U -> G1(s+1) --------
        G1_BODY(tT[0]);
        barrier_lds();
        for (int s = 0; s < NSTEP; ++s) {
            float nz0 = noises[(grow * NSTEP + s) * ZD + uc0];
            float nz1 = noises[(grow * NSTEP + s) * ZD + uc1];
            G2_BODY();
            barrier_lds();
            U_BODY(s, nz0, nz1);
            barrier_lds();
            if (s + 1 < NSTEP) G1_BODY(tT[s + 1]);
            barrier_lds();
        }
    } else {
        // -------- half B: G1 -> G2 -> U --------
        barrier_lds();
        for (int s = 0; s < NSTEP; ++s) {
            G1_BODY(tT[s]);
            barrier_lds();
            float nz0 = noises[(grow * NSTEP + s) * ZD + uc0];
            float nz1 = noises[(grow * NSTEP + s) * ZD + uc1];
            G2_BODY();
            barrier_lds();
            U_BODY(s, nz0, nz1);
            barrier_lds();
        }
    }

    // ---- finalize: log_weights and nabla_g (per-group data, no barrier) ----
    {
        float m0 = mu[uc0], m1 = mu[uc1];
        float d0 = xu0 - m0, d1 = xu1 - m1;
        out[NG_OFF + grow * ZD + uc0] = d0 - xu0;    // == -mu
        out[NG_OFF + grow * ZD + uc1] = d1 - xu1;
        float part = lw + 0.5f * (xu0 * xu0 + xu1 * xu1)
                   - 0.5f * (d0 * d0 + d1 * d1);
        part += __shfl_xor(part, 1, 64);
        part += __shfl_xor(part, 2, 64);
        part += __shfl_xor(part, 4, 64);
        part += __shfl_xor(part, 8, 64);
        part += __shfl_xor(part, 16, 64);
        if ((lane & 31) == 0) out[LW_OFF + grow] = part;
    }
#undef G1_BODY
#undef G2_BODY
#undef U_BODY
}

extern "C" void kernel_launch(void* const* d_in, const int* in_sizes, int n_in,
                              void* d_out, int out_size, void* d_ws, size_t ws_size,
                              hipStream_t stream) {
    const float* r      = (const float*)d_in[0];
    const float* noises = (const float*)d_in[1];
    const float* x0     = (const float*)d_in[2];
    const float* W1     = (const float*)d_in[3];
    const float* b1     = (const float*)d_in[4];
    const float* W2     = (const float*)d_in[5];
    const float* b2     = (const float*)d_in[6];
    const float* bmax   = (const float*)d_in[7];
    const float* bmin   = (const float*)d_in[8];
    const float* mu     = (const float*)d_in[9];
    float* out = (float*)d_out;

    sim_kernel<<<256, 1024, 0, stream>>>(r, noises, x0, W1, b1, W2, b2,
                                         bmax, bmin, mu, out);
}

// Round 15
// 223.443 us; speedup vs baseline: 1.3218x; 1.3218x over previous
//
#include <hip/hip_runtime.h>

#define ZD 64
#define RD 128
#define HIDDEN 512
#define NSTEP 100
#define OUT_PITCH 6464              // 101*64
#define DT_F 0.01f
#define ROWS 16
#define HSTR 520                    // Hs row stride (shorts), <=2-way banks
#define XSTR 72                     // Xb row stride (shorts)
#define PSTR 76                     // Ps row stride (floats)

static const size_t LW_OFF = 52953088ull;   // 8192*101*64
static const size_t NG_OFF = 52961280ull;   // + 8192

typedef __attribute__((ext_vector_type(2))) float  f32x2;
typedef __attribute__((ext_vector_type(4))) float  f32x4;
typedef __attribute__((ext_vector_type(8))) __bf16 bf16x8;
typedef __attribute__((ext_vector_type(2))) short  s16x2;
typedef __attribute__((ext_vector_type(4))) short  s16x4;
typedef __attribute__((ext_vector_type(8))) short  s16x8;

__device__ __forceinline__ short f2bs(float f) {
    return __builtin_bit_cast(short, (__bf16)f);
}
__device__ __forceinline__ float bs2f(short s) {
    return __builtin_bit_cast(float, ((unsigned)(unsigned short)s) << 16);
}
__device__ __forceinline__ float tanh_fast(float x) {
    float e = __builtin_amdgcn_exp2f(x * 2.88539008177793f);
    float r = __builtin_amdgcn_rcpf(e + 1.0f);
    return fmaf(-2.0f, r, 1.0f);
}

// ---------------------------------------------------------------------------
// sim_kernel: persistent scan. 512 blocks x 512 threads (8 waves), 16 rows
// per block -> TWO co-resident blocks/CU with independent barrier domains
// that drift out of phase: block A's VALU-heavy G1 overlaps block B's
// DS-heavy G2/U. waves_per_eu(4,8) pins the combined VGPR+AGPR cap at 128;
// this shape's demand ~107 (w1f 32 + w2f 32 AGPR-eligible, prefb 8 packed,
// ~35 temps; single m-tile -> only 2 xb reads) so no spills expected.
// GEMM1: 8 waves x 4 n-tiles. GEMM2: (zh x kq), each h read feeds 2 z-tiles;
// Ps[4] partials (padded stride 76, <=2-way banks), summed in update.
// ---------------------------------------------------------------------------
__global__ __launch_bounds__(512)
__attribute__((amdgpu_waves_per_eu(4, 8)))
void sim_kernel(
    const float* __restrict__ r, const float* __restrict__ noises,
    const float* __restrict__ x0, const float* __restrict__ W1,
    const float* __restrict__ b1, const float* __restrict__ W2,
    const float* __restrict__ b2, const float* __restrict__ bmax,
    const float* __restrict__ bmin, const float* __restrict__ mu,
    float* __restrict__ out)
{
    __shared__ float Ps[4][ROWS][PSTR];               // 19456 B
    __shared__ unsigned short Xb[ROWS * XSTR];        // 2304 B
    __shared__ unsigned short Hs[ROWS * HSTR];        // 16640 B
    __shared__ float w1ts[HIDDEN];                    // 2048 B
    __shared__ float tT[NSTEP], tG[NSTEP], tSd[NSTEP], tCd[NSTEP], tCs[NSTEP];

    const int tid  = threadIdx.x;
    const int lane = tid & 63;
    const int wave = tid >> 6;       // 0..7
    const int g4   = lane >> 4;      // 0..3
    const int l16  = lane & 15;
    const int row0 = blockIdx.x * ROWS;

    // ---- step tables ----
    if (tid < NSTEP) {
        float spmax = log1pf(expf(bmax[0]));
        float spmin = log1pf(expf(bmin[0]));
        float a_ = spmax - spmin;
        float c_ = spmin;
        const float PI_ = 3.14159265358979323846f;
        float k = (float)tid;
        float t0 = k * DT_F, t1 = (k + 1.0f) * DT_F;
        float inv2pi = 1.0f / (2.0f * PI_);
        float F0 = a_ * sinf(PI_ * t0) * inv2pi + (0.5f * a_ + c_) * t0;
        float F1 = a_ * sinf(PI_ * t1) * inv2pi + (0.5f * a_ + c_) * t1;
        float al = 1.0f - expf(-2.0f * (F1 - F0));
        float gg = 1.0f - sqrtf(1.0f - al);
        float kap = (gg * gg) / al;
        tT[tid] = t0; tG[tid] = gg; tSd[tid] = sqrtf(al);
        tCd[tid] = -2.0f * kap; tCs[tid] = -2.0f * sqrtf(kap);
    }
    w1ts[tid] = W1[(size_t)192 * HIDDEN + tid];

    // ---- x state init (update-thread registers) + x_t[:,0,:] + Xb ----
    const int urow = tid >> 5;          // 0..15
    const int c2   = (tid & 31) * 2;    // 0..62
    const size_t ubase = (size_t)(row0 + urow);
    float xr0, xr1;
    {
        f32x2 v = *(const f32x2*)(x0 + ubase * ZD + c2);
        xr0 = v[0]; xr1 = v[1];
        *(f32x2*)(out + ubase * OUT_PITCH + c2) = v;
        s16x2 xv; xv[0] = f2bs(xr0); xv[1] = f2bs(xr1);
        *(s16x2*)(Xb + urow * XSTR + c2) = xv;
    }
    const float bb0 = b2[c2], bb1 = b2[c2 + 1];

    // ---- pre-fragments via MFMA: prefb = bf16(b1 + r @ W1r), packed ----
    s16x4 prefb[4];
    {
        bf16x8 rf[4];
        const float* rp = r + (size_t)(row0 + l16) * RD;
        #pragma unroll
        for (int kc = 0; kc < 4; ++kc) {
            f32x4 lo = *(const f32x4*)(rp + kc * 32 + g4 * 8);
            f32x4 hi = *(const f32x4*)(rp + kc * 32 + g4 * 8 + 4);
            bf16x8 v;
            v[0]=(__bf16)lo[0]; v[1]=(__bf16)lo[1]; v[2]=(__bf16)lo[2]; v[3]=(__bf16)lo[3];
            v[4]=(__bf16)hi[0]; v[5]=(__bf16)hi[1]; v[6]=(__bf16)hi[2]; v[7]=(__bf16)hi[3];
            rf[kc] = v;
        }
        #pragma unroll
        for (int j2 = 0; j2 < 4; ++j2) {
            int n  = (wave * 4 + j2) * 16 + l16;
            int n0 = (wave * 4 + j2) * 16 + g4 * 4;
            f32x4 acc = *(const f32x4*)(b1 + n0);
            #pragma unroll
            for (int kc = 0; kc < 4; ++kc) {
                bf16x8 w;
                #pragma unroll
                for (int j = 0; j < 8; ++j)
                    w[j] = (__bf16)W1[(size_t)(64 + kc * 32 + g4 * 8 + j) * HIDDEN + n];
                acc = __builtin_amdgcn_mfma_f32_16x16x32_bf16(w, rf[kc], acc, 0, 0, 0);
            }
            s16x4 pb;
            pb[0] = f2bs(acc[0]); pb[1] = f2bs(acc[1]);
            pb[2] = f2bs(acc[2]); pb[3] = f2bs(acc[3]);
            prefb[j2] = pb;
        }
    }

    // ---- persistent weight fragments (MFMA-only -> AGPR-eligible) ----
    bf16x8 w1f[4][2];                // [j2][kc]
    #pragma unroll
    for (int j2 = 0; j2 < 4; ++j2) {
        int n = (wave * 4 + j2) * 16 + l16;
        #pragma unroll
        for (int kc = 0; kc < 2; ++kc) {
            bf16x8 v;
            #pragma unroll
            for (int j = 0; j < 8; ++j)
                v[j] = (__bf16)W1[(size_t)(kc * 32 + g4 * 8 + j) * HIDDEN + n];
            w1f[j2][kc] = v;
        }
    }
    // GEMM2 roles: zh = wave&1 (z-half), kq = wave>>1 (K-quarter).
    const int zh = wave & 1, kq = wave >> 1;
    bf16x8 w2f[2][4];
    #pragma unroll
    for (int zt2 = 0; zt2 < 2; ++zt2) {
        int n = (zh * 2 + zt2) * 16 + l16;
        #pragma unroll
        for (int i = 0; i < 4; ++i) {
            bf16x8 v;
            #pragma unroll
            for (int j = 0; j < 8; ++j)
                v[j] = (__bf16)W2[(size_t)(kq * 128 + i * 32 + g4 * 8 + j) * ZD + n];
            w2f[zt2][i] = v;
        }
    }

    float lwacc = 0.0f;

    __syncthreads();

    for (int s = 0; s < NSTEP; ++s) {
        float t = tT[s];
        // noise prefetch for update phase (hidden under 2 barriers)
        f32x2 nz = *(const f32x2*)(noises + (ubase * NSTEP + s) * ZD + c2);

        // ================= GEMM1: h = tanh(x@W1x + pre + t*w1t) ============
        {
            s16x8 xb0 = *(const s16x8*)(Xb + l16 * XSTR + g4 * 8);
            s16x8 xb1 = *(const s16x8*)(Xb + l16 * XSTR + 32 + g4 * 8);
            #pragma unroll
            for (int j2 = 0; j2 < 4; ++j2) {
                int n0 = (wave * 4 + j2) * 16 + g4 * 4;
                f32x4 wt = *(const f32x4*)(w1ts + n0);
                s16x4 pb = prefb[j2];
                f32x4 acc;
                acc[0] = fmaf(t, wt[0], bs2f(pb[0]));
                acc[1] = fmaf(t, wt[1], bs2f(pb[1]));
                acc[2] = fmaf(t, wt[2], bs2f(pb[2]));
                acc[3] = fmaf(t, wt[3], bs2f(pb[3]));
                acc = __builtin_amdgcn_mfma_f32_16x16x32_bf16(
                    w1f[j2][0], __builtin_bit_cast(bf16x8, xb0), acc, 0, 0, 0);
                acc = __builtin_amdgcn_mfma_f32_16x16x32_bf16(
                    w1f[j2][1], __builtin_bit_cast(bf16x8, xb1), acc, 0, 0, 0);
                s16x4 hv;
                hv[0] = f2bs(tanh_fast(acc[0]));
                hv[1] = f2bs(tanh_fast(acc[1]));
                hv[2] = f2bs(tanh_fast(acc[2]));
                hv[3] = f2bs(tanh_fast(acc[3]));
                *(s16x4*)(Hs + l16 * HSTR + n0) = hv;
            }
        }
        __syncthreads();

        // ====== GEMM2 (z-half x K-quarter): partials -> Ps[kq] =============
        {
            int base = l16 * HSTR + kq * 128 + g4 * 8;
            f32x4 aA = { 0.f, 0.f, 0.f, 0.f };
            f32x4 aB = { 0.f, 0.f, 0.f, 0.f };
            #pragma unroll
            for (int i = 0; i < 4; ++i) {
                s16x8 h = *(const s16x8*)(Hs + base + i * 32);
                aA = __builtin_amdgcn_mfma_f32_16x16x32_bf16(
                    w2f[0][i], __builtin_bit_cast(bf16x8, h), aA, 0, 0, 0);
                aB = __builtin_amdgcn_mfma_f32_16x16x32_bf16(
                    w2f[1][i], __builtin_bit_cast(bf16x8, h), aB, 0, 0, 0);
            }
            *(f32x4*)(&Ps[kq][l16][(zh * 2 + 0) * 16 + g4 * 4]) = aA;
            *(f32x4*)(&Ps[kq][l16][(zh * 2 + 1) * 16 + g4 * 4]) = aB;
        }
        __syncthreads();

        // ================= Update (x in registers, lw deferred) ============
        {
            float gg = tG[s], sdv = tSd[s], cd = tCd[s], cs = tCs[s];
            f32x2 p0 = *(const f32x2*)(&Ps[0][urow][c2]);
            f32x2 p1 = *(const f32x2*)(&Ps[1][urow][c2]);
            f32x2 p2 = *(const f32x2*)(&Ps[2][urow][c2]);
            f32x2 p3 = *(const f32x2*)(&Ps[3][urow][c2]);
            float s0 = ((p0[0] + p1[0]) + (p2[0] + p3[0])) + bb0;
            float s1 = ((p0[1] + p1[1]) + (p2[1] + p3[1])) + bb1;
            float xn0 = xr0 + gg * (2.0f * s0 - xr0) + sdv * nz[0];
            float xn1 = xr1 + gg * (2.0f * s1 - xr1) + sdv * nz[1];
            xr0 = xn0; xr1 = xn1;
            f32x2 xv = { xn0, xn1 };
            *(f32x2*)(out + ubase * OUT_PITCH + (size_t)(s + 1) * ZD + c2) = xv;
            s16x2 xb2; xb2[0] = f2bs(xn0); xb2[1] = f2bs(xn1);
            *(s16x2*)(Xb + urow * XSTR + c2) = xb2;
            lwacc += cd * (s0 * s0 + s1 * s1) + cs * (s0 * nz[0] + s1 * nz[1]);
        }
        __syncthreads();
    }

    // ---- finalize: log_weights and nabla_g ----
    {
        float m0 = mu[c2], m1 = mu[c2 + 1];
        float d0 = xr0 - m0, d1 = xr1 - m1;
        f32x2 ng = { d0 - xr0, d1 - xr1 };           // == -mu
        *(f32x2*)(out + NG_OFF + ubase * ZD + c2) = ng;
        float part = lwacc
                   + 0.5f * (xr0 * xr0 + xr1 * xr1) - 0.5f * (d0 * d0 + d1 * d1);
        part += __shfl_xor(part, 1, 64);
        part += __shfl_xor(part, 2, 64);
        part += __shfl_xor(part, 4, 64);
        part += __shfl_xor(part, 8, 64);
        part += __shfl_xor(part, 16, 64);
        if ((tid & 31) == 0) out[LW_OFF + ubase] = part;
    }
}

extern "C" void kernel_launch(void* const* d_in, const int* in_sizes, int n_in,
                              void* d_out, int out_size, void* d_ws, size_t ws_size,
                              hipStream_t stream) {
    const float* r      = (const float*)d_in[0];
    const float* noises = (const float*)d_in[1];
    const float* x0     = (const float*)d_in[2];
    const float* W1     = (const float*)d_in[3];
    const float* b1     = (const float*)d_in[4];
    const float* W2     = (const float*)d_in[5];
    const float* b2     = (const float*)d_in[6];
    const float* bmax   = (const float*)d_in[7];
    const float* bmin   = (const float*)d_in[8];
    const float* mu     = (const float*)d_in[9];
    float* out = (float*)d_out;

    sim_kernel<<<512, 512, 0, stream>>>(r, noises, x0, W1, b1, W2, b2,
                                        bmax, bmin, mu, out);
}